// Round 1
// baseline (1153.709 us; speedup 1.0000x reference)
//
#include <hip/hip_runtime.h>
#include <hip/hip_bf16.h>

#define N_NODES 50000
#define N_EDGES 800000
#define E_TOTAL (N_EDGES + N_NODES)
#define HEADS 8
#define HD 16
#define C 128            // HEADS*HD == IN_CH
#define NEG_SLOPE 0.2f
#define BN_EPS 1e-5f
#define SCAN_BLKS ((N_NODES + 255) / 256)

// ---- monotone float<->uint encoding for atomicMax on floats ----
__device__ __forceinline__ unsigned fenc(float f) {
  unsigned u = __float_as_uint(f);
  return (u & 0x80000000u) ? ~u : (u | 0x80000000u);
}
__device__ __forceinline__ float fdec(unsigned k) {
  unsigned u = (k & 0x80000000u) ? (k ^ 0x80000000u) : ~k;
  return __uint_as_float(u);
}

// ---- 1) h = x @ W  (+ per-head a_src/a_dst reductions) ----
// block = 128 threads (thread o = output channel), 8 nodes per block
__global__ __launch_bounds__(128) void k_gemm_att(
    const float* __restrict__ x, const float* __restrict__ W,
    const float* __restrict__ att_src, const float* __restrict__ att_dst,
    float* __restrict__ h, float* __restrict__ a_src, float* __restrict__ a_dst) {
  __shared__ float xs[8 * C];
  const int t = threadIdx.x;
  const int node0 = blockIdx.x * 8;
  const float* xsrc = x + (size_t)node0 * C;
#pragma unroll
  for (int i = 0; i < 8; ++i) xs[t + i * 128] = xsrc[t + i * 128];
  __syncthreads();

  float acc[8] = {0.f, 0.f, 0.f, 0.f, 0.f, 0.f, 0.f, 0.f};
  for (int k4 = 0; k4 < 32; ++k4) {
    const float w0 = W[(4 * k4 + 0) * C + t];
    const float w1 = W[(4 * k4 + 1) * C + t];
    const float w2 = W[(4 * k4 + 2) * C + t];
    const float w3 = W[(4 * k4 + 3) * C + t];
#pragma unroll
    for (int n = 0; n < 8; ++n) {
      const float4 xq = *(const float4*)&xs[n * C + 4 * k4];
      acc[n] = fmaf(xq.w, w3, fmaf(xq.z, w2, fmaf(xq.y, w1, fmaf(xq.x, w0, acc[n]))));
    }
  }

  const float asv = att_src[t];
  const float adv = att_dst[t];
#pragma unroll
  for (int n = 0; n < 8; ++n) {
    const int node = node0 + n;
    h[(size_t)node * C + t] = acc[n];
    float s = acc[n] * asv;
    float d = acc[n] * adv;
#pragma unroll
    for (int off = 8; off >= 1; off >>= 1) {
      s += __shfl_xor(s, off, 16);
      d += __shfl_xor(d, off, 16);
    }
    if ((t & 15) == 0) {
      a_src[node * HEADS + (t >> 4)] = s;
      a_dst[node * HEADS + (t >> 4)] = d;
    }
  }
}

// ---- 2) histogram of dst degrees (incl. self loops) ----
__global__ void k_hist(const int* __restrict__ ei, int* __restrict__ counts) {
  const int e = blockIdx.x * blockDim.x + threadIdx.x;
  if (e >= E_TOTAL) return;
  const int dst = (e < N_EDGES) ? ei[N_EDGES + e] : (e - N_EDGES);
  atomicAdd(&counts[dst], 1);
}

// ---- 3) exclusive scan of counts -> offs (3 small kernels) ----
__global__ __launch_bounds__(256) void k_scan1(const int* __restrict__ counts,
                                               int* __restrict__ offs,
                                               int* __restrict__ bsums) {
  __shared__ int s[256];
  const int t = threadIdx.x;
  const int i = blockIdx.x * 256 + t;
  const int c = (i < N_NODES) ? counts[i] : 0;
  s[t] = c;
  __syncthreads();
  for (int off = 1; off < 256; off <<= 1) {
    int v = 0;
    if (t >= off) v = s[t - off];
    __syncthreads();
    if (t >= off) s[t] += v;
    __syncthreads();
  }
  if (i < N_NODES) offs[i] = s[t] - c;
  if (t == 255) bsums[blockIdx.x] = s[255];
}

__global__ __launch_bounds__(256) void k_scan2(int* __restrict__ bsums) {
  __shared__ int s[256];
  const int t = threadIdx.x;
  const int c = (t < SCAN_BLKS) ? bsums[t] : 0;
  s[t] = c;
  __syncthreads();
  for (int off = 1; off < 256; off <<= 1) {
    int v = 0;
    if (t >= off) v = s[t - off];
    __syncthreads();
    if (t >= off) s[t] += v;
    __syncthreads();
  }
  if (t < SCAN_BLKS) bsums[t] = s[t] - c;
}

__global__ __launch_bounds__(256) void k_scan3(int* __restrict__ offs,
                                               const int* __restrict__ bsums) {
  const int i = blockIdx.x * 256 + threadIdx.x;
  if (i < N_NODES) offs[i] += bsums[blockIdx.x];
}

// ---- 4) fill CSR (sorted-by-dst edge list) + segment max of logits ----
__global__ void k_edge_fill(const int* __restrict__ ei,
                            const float* __restrict__ a_src,
                            const float* __restrict__ a_dst,
                            const int* __restrict__ offs, int* __restrict__ cursor,
                            int* __restrict__ srcs_s, int* __restrict__ dsts_s,
                            unsigned* __restrict__ mkey) {
  const int e = blockIdx.x * blockDim.x + threadIdx.x;
  if (e >= E_TOTAL) return;
  int src, dst;
  if (e < N_EDGES) {
    src = ei[e];
    dst = ei[N_EDGES + e];
  } else {
    src = dst = e - N_EDGES;
  }
  const int pos = offs[dst] + atomicAdd(&cursor[dst], 1);
  srcs_s[pos] = src;
  dsts_s[pos] = dst;
  const float* as = a_src + src * HEADS;
  const float* ad = a_dst + dst * HEADS;
#pragma unroll
  for (int hh = 0; hh < HEADS; ++hh) {
    float v = as[hh] + ad[hh];
    v = (v > 0.f) ? v : NEG_SLOPE * v;
    atomicMax(&mkey[dst * HEADS + hh], fenc(v));
  }
}

// ---- 5) exp(e - m) into sorted slots + denominator ----
__global__ void k_edge_exp(const int* __restrict__ srcs_s, const int* __restrict__ dsts_s,
                           const float* __restrict__ a_src, const float* __restrict__ a_dst,
                           const unsigned* __restrict__ mkey,
                           float* __restrict__ ex_s, float* __restrict__ denom) {
  const int p = blockIdx.x * blockDim.x + threadIdx.x;
  if (p >= E_TOTAL) return;
  const int src = srcs_s[p];
  const int dst = dsts_s[p];
#pragma unroll
  for (int hh = 0; hh < HEADS; ++hh) {
    float v = a_src[src * HEADS + hh] + a_dst[dst * HEADS + hh];
    v = (v > 0.f) ? v : NEG_SLOPE * v;
    const float m = fdec(mkey[dst * HEADS + hh]);
    const float ex = __expf(v - m);
    ex_s[p * HEADS + hh] = ex;
    atomicAdd(&denom[dst * HEADS + hh], ex);
  }
}

// ---- 6) gather-aggregate per dst node + bias + BN partial sums ----
// block = 128 threads (one per channel), 8 nodes per block
__global__ __launch_bounds__(128) void k_agg(
    const float* __restrict__ h, const int* __restrict__ srcs_s,
    const float* __restrict__ ex_s, const int* __restrict__ offs,
    const int* __restrict__ counts, const float* __restrict__ denom,
    const float* __restrict__ bias, float* __restrict__ out,
    float* __restrict__ bnsum, float* __restrict__ bnsq) {
  const int t = threadIdx.x;
  const int hh = t >> 4;
  const float bv = bias[t];
  float bs = 0.f, bs2 = 0.f;
#pragma unroll 1
  for (int n = 0; n < 8; ++n) {
    const int node = blockIdx.x * 8 + n;
    const int beg = offs[node];
    const int end = beg + counts[node];
    float acc = 0.f;
    for (int j = beg; j < end; ++j) {
      const int s = srcs_s[j];
      const float exv = ex_s[j * HEADS + hh];
      acc = fmaf(exv, h[(size_t)s * C + t], acc);
    }
    const float dn = denom[node * HEADS + hh];
    const float val = acc / (dn + 1e-16f) + bv;
    out[(size_t)node * C + t] = val;
    bs += val;
    bs2 += val * val;
  }
  atomicAdd(&bnsum[t], bs);
  atomicAdd(&bnsq[t], bs2);
}

// ---- 7) finalize BN scale/shift ----
__global__ __launch_bounds__(128) void k_bnfin(const float* __restrict__ bnsum,
                                               const float* __restrict__ bnsq,
                                               const float* __restrict__ gamma,
                                               const float* __restrict__ beta,
                                               float* __restrict__ scale,
                                               float* __restrict__ shift) {
  const int t = threadIdx.x;
  const float invN = 1.0f / (float)N_NODES;
  const float mean = bnsum[t] * invN;
  const float var = bnsq[t] * invN - mean * mean;
  const float sc = gamma[t] * rsqrtf(var + BN_EPS);
  scale[t] = sc;
  shift[t] = beta[t] - mean * sc;
}

// ---- 8) normalize + ReLU (elementwise, float4) ----
__global__ __launch_bounds__(256) void k_norm(float* __restrict__ out,
                                              const float* __restrict__ scale,
                                              const float* __restrict__ shift) {
  const int i = blockIdx.x * blockDim.x + threadIdx.x;
  if (i >= N_NODES * C / 4) return;
  float4 v = ((float4*)out)[i];
  const int c4 = i & 31;
  const float4 sc = ((const float4*)scale)[c4];
  const float4 sh = ((const float4*)shift)[c4];
  v.x = fmaxf(0.f, fmaf(v.x, sc.x, sh.x));
  v.y = fmaxf(0.f, fmaf(v.y, sc.y, sh.y));
  v.z = fmaxf(0.f, fmaf(v.z, sc.z, sh.z));
  v.w = fmaxf(0.f, fmaf(v.w, sc.w, sh.w));
  ((float4*)out)[i] = v;
}

extern "C" void kernel_launch(void* const* d_in, const int* in_sizes, int n_in,
                              void* d_out, int out_size, void* d_ws, size_t ws_size,
                              hipStream_t stream) {
  const float* x = (const float*)d_in[0];
  const int* ei = (const int*)d_in[1];
  const float* W = (const float*)d_in[2];
  const float* att_src = (const float*)d_in[3];
  const float* att_dst = (const float*)d_in[4];
  const float* bias = (const float*)d_in[5];
  const float* gamma = (const float*)d_in[6];
  const float* beta = (const float*)d_in[7];
  float* out = (float*)d_out;

  char* base = (char*)d_ws;
  size_t off = 0;
  auto alloc = [&](size_t bytes) {
    void* p = base + off;
    off = (off + bytes + 255) & ~(size_t)255;
    return p;
  };

  float* h = (float*)alloc((size_t)N_NODES * C * 4);
  float* a_src = (float*)alloc((size_t)N_NODES * HEADS * 4);
  float* a_dst = (float*)alloc((size_t)N_NODES * HEADS * 4);
  int* srcs_s = (int*)alloc((size_t)E_TOTAL * 4);
  int* dsts_s = (int*)alloc((size_t)E_TOTAL * 4);
  float* ex_s = (float*)alloc((size_t)E_TOTAL * HEADS * 4);
  int* offs = (int*)alloc((size_t)N_NODES * 4);
  int* bsums = (int*)alloc(256 * 4);
  float* scale = (float*)alloc(C * 4);
  float* shift = (float*)alloc(C * 4);
  // ---- zeroed region (single memset) ----
  const size_t zoff = off;
  unsigned* mkey = (unsigned*)alloc((size_t)N_NODES * HEADS * 4);
  float* denom = (float*)alloc((size_t)N_NODES * HEADS * 4);
  int* counts = (int*)alloc((size_t)N_NODES * 4);
  int* cursor = (int*)alloc((size_t)N_NODES * 4);
  float* bnsum = (float*)alloc(C * 4);
  float* bnsq = (float*)alloc(C * 4);
  const size_t zbytes = off - zoff;
  hipMemsetAsync(base + zoff, 0, zbytes, stream);

  k_gemm_att<<<N_NODES / 8, 128, 0, stream>>>(x, W, att_src, att_dst, h, a_src, a_dst);
  k_hist<<<(E_TOTAL + 255) / 256, 256, 0, stream>>>(ei, counts);
  k_scan1<<<SCAN_BLKS, 256, 0, stream>>>(counts, offs, bsums);
  k_scan2<<<1, 256, 0, stream>>>(bsums);
  k_scan3<<<SCAN_BLKS, 256, 0, stream>>>(offs, bsums);
  k_edge_fill<<<(E_TOTAL + 255) / 256, 256, 0, stream>>>(ei, a_src, a_dst, offs, cursor,
                                                         srcs_s, dsts_s, mkey);
  k_edge_exp<<<(E_TOTAL + 255) / 256, 256, 0, stream>>>(srcs_s, dsts_s, a_src, a_dst,
                                                        mkey, ex_s, denom);
  k_agg<<<N_NODES / 8, 128, 0, stream>>>(h, srcs_s, ex_s, offs, counts, denom, bias, out,
                                         bnsum, bnsq);
  k_bnfin<<<1, 128, 0, stream>>>(bnsum, bnsq, gamma, beta, scale, shift);
  k_norm<<<(N_NODES * C / 4 + 255) / 256, 256, 0, stream>>>(out, scale, shift);
}

// Round 5
// 454.534 us; speedup vs baseline: 2.5382x; 2.5382x over previous
//
#include <hip/hip_runtime.h>
#include <hip/hip_bf16.h>

#define N_NODES 50000
#define N_EDGES 800000
#define E_TOTAL (N_EDGES + N_NODES)
#define HEADS 8
#define HD 16
#define C 128            // HEADS*HD == IN_CH
#define NEG_SLOPE 0.2f
#define BN_EPS 1e-5f
#define SCAN_BLKS ((N_NODES + 255) / 256)

// ---- 1) h = x @ W  (+ per-head a_src/a_dst reductions) ----
// block = 128 threads (thread o = output channel), 8 nodes per block
__global__ __launch_bounds__(128) void k_gemm_att(
    const float* __restrict__ x, const float* __restrict__ W,
    const float* __restrict__ att_src, const float* __restrict__ att_dst,
    float* __restrict__ h, float* __restrict__ a_src, float* __restrict__ a_dst) {
  __shared__ float xs[8 * C];
  const int t = threadIdx.x;
  const int node0 = blockIdx.x * 8;
  const float* xsrc = x + (size_t)node0 * C;
#pragma unroll
  for (int i = 0; i < 8; ++i) xs[t + i * 128] = xsrc[t + i * 128];
  __syncthreads();

  float acc[8] = {0.f, 0.f, 0.f, 0.f, 0.f, 0.f, 0.f, 0.f};
  for (int k4 = 0; k4 < 32; ++k4) {
    const float w0 = W[(4 * k4 + 0) * C + t];
    const float w1 = W[(4 * k4 + 1) * C + t];
    const float w2 = W[(4 * k4 + 2) * C + t];
    const float w3 = W[(4 * k4 + 3) * C + t];
#pragma unroll
    for (int n = 0; n < 8; ++n) {
      const float4 xq = *(const float4*)&xs[n * C + 4 * k4];
      acc[n] = fmaf(xq.w, w3, fmaf(xq.z, w2, fmaf(xq.y, w1, fmaf(xq.x, w0, acc[n]))));
    }
  }

  const float asv = att_src[t];
  const float adv = att_dst[t];
#pragma unroll
  for (int n = 0; n < 8; ++n) {
    const int node = node0 + n;
    h[(size_t)node * C + t] = acc[n];
    float s = acc[n] * asv;
    float d = acc[n] * adv;
#pragma unroll
    for (int off = 8; off >= 1; off >>= 1) {
      s += __shfl_xor(s, off, 16);
      d += __shfl_xor(d, off, 16);
    }
    if ((t & 15) == 0) {
      a_src[node * HEADS + (t >> 4)] = s;
      a_dst[node * HEADS + (t >> 4)] = d;
    }
  }
}

// ---- 2) histogram of dst degrees (incl. self loops) ----
__global__ void k_hist(const int* __restrict__ ei, int* __restrict__ counts) {
  const int e = blockIdx.x * blockDim.x + threadIdx.x;
  if (e >= E_TOTAL) return;
  const int dst = (e < N_EDGES) ? ei[N_EDGES + e] : (e - N_EDGES);
  atomicAdd(&counts[dst], 1);
}

// ---- 3) exclusive scan of counts -> offs (3 small kernels) ----
__global__ __launch_bounds__(256) void k_scan1(const int* __restrict__ counts,
                                               int* __restrict__ offs,
                                               int* __restrict__ bsums) {
  __shared__ int s[256];
  const int t = threadIdx.x;
  const int i = blockIdx.x * 256 + t;
  const int c = (i < N_NODES) ? counts[i] : 0;
  s[t] = c;
  __syncthreads();
  for (int off = 1; off < 256; off <<= 1) {
    int v = 0;
    if (t >= off) v = s[t - off];
    __syncthreads();
    if (t >= off) s[t] += v;
    __syncthreads();
  }
  if (i < N_NODES) offs[i] = s[t] - c;
  if (t == 255) bsums[blockIdx.x] = s[255];
}

__global__ __launch_bounds__(256) void k_scan2(int* __restrict__ bsums) {
  __shared__ int s[256];
  const int t = threadIdx.x;
  const int c = (t < SCAN_BLKS) ? bsums[t] : 0;
  s[t] = c;
  __syncthreads();
  for (int off = 1; off < 256; off <<= 1) {
    int v = 0;
    if (t >= off) v = s[t - off];
    __syncthreads();
    if (t >= off) s[t] += v;
    __syncthreads();
  }
  if (t < SCAN_BLKS) bsums[t] = s[t] - c;
}

__global__ __launch_bounds__(256) void k_scan3(int* __restrict__ offs,
                                               const int* __restrict__ bsums) {
  const int i = blockIdx.x * 256 + threadIdx.x;
  if (i < N_NODES) offs[i] += bsums[blockIdx.x];
}

// ---- 4) fill CSR (sorted-by-dst source list). No per-head atomics. ----
__global__ void k_edge_fill(const int* __restrict__ ei,
                            const int* __restrict__ offs, int* __restrict__ cursor,
                            int* __restrict__ srcs_s) {
  const int e = blockIdx.x * blockDim.x + threadIdx.x;
  if (e >= E_TOTAL) return;
  int src, dst;
  if (e < N_EDGES) {
    src = ei[e];
    dst = ei[N_EDGES + e];
  } else {
    src = dst = e - N_EDGES;
  }
  const int pos = offs[dst] + atomicAdd(&cursor[dst], 1);
  srcs_s[pos] = src;
}

// ---- 5) gather: softmax (max+denom in registers) + weighted aggregate ----
// block = 128 threads (one per channel), 8 nodes per block
__global__ __launch_bounds__(128) void k_agg(
    const float* __restrict__ h, const int* __restrict__ srcs_s,
    const float* __restrict__ a_src, const float* __restrict__ a_dst,
    const int* __restrict__ offs, const int* __restrict__ counts,
    const float* __restrict__ bias, float* __restrict__ out,
    float* __restrict__ bnsum, float* __restrict__ bnsq) {
  const int t = threadIdx.x;
  const int hh = t >> 4;
  const int l16 = t & 15;
  const float bv = bias[t];
  float bs = 0.f, bs2 = 0.f;
#pragma unroll 1
  for (int n = 0; n < 8; ++n) {
    const int node = blockIdx.x * 8 + n;
    const int beg = offs[node];
    const int end = beg + counts[node];
    const float adv = a_dst[node * HEADS + hh];

    // pass 1: segment max of leaky-relu logits (16 lanes of the head group)
    float mx = -1e30f;
    for (int j = beg + l16; j < end; j += 16) {
      const int s = srcs_s[j];
      float v = a_src[s * HEADS + hh] + adv;
      v = (v > 0.f) ? v : NEG_SLOPE * v;
      mx = fmaxf(mx, v);
    }
#pragma unroll
    for (int off = 8; off >= 1; off >>= 1) mx = fmaxf(mx, __shfl_xor(mx, off, 16));

    // pass 2: exp + denom (redundant per head group) + weighted h accumulate
    float acc = 0.f, den = 0.f;
    for (int j = beg; j < end; ++j) {
      const int s = srcs_s[j];
      float v = a_src[s * HEADS + hh] + adv;
      v = (v > 0.f) ? v : NEG_SLOPE * v;
      const float ex = __expf(v - mx);
      den += ex;
      acc = fmaf(ex, h[(size_t)s * C + t], acc);
    }
    const float val = acc / (den + 1e-16f) + bv;
    out[(size_t)node * C + t] = val;
    bs += val;
    bs2 += val * val;
  }
  atomicAdd(&bnsum[t], bs);
  atomicAdd(&bnsq[t], bs2);
}

// ---- 6) finalize BN scale/shift ----
__global__ __launch_bounds__(128) void k_bnfin(const float* __restrict__ bnsum,
                                               const float* __restrict__ bnsq,
                                               const float* __restrict__ gamma,
                                               const float* __restrict__ beta,
                                               float* __restrict__ scale,
                                               float* __restrict__ shift) {
  const int t = threadIdx.x;
  const float invN = 1.0f / (float)N_NODES;
  const float mean = bnsum[t] * invN;
  const float var = bnsq[t] * invN - mean * mean;
  const float sc = gamma[t] * rsqrtf(var + BN_EPS);
  scale[t] = sc;
  shift[t] = beta[t] - mean * sc;
}

// ---- 7) normalize + ReLU (elementwise, float4) ----
__global__ __launch_bounds__(256) void k_norm(float* __restrict__ out,
                                              const float* __restrict__ scale,
                                              const float* __restrict__ shift) {
  const int i = blockIdx.x * blockDim.x + threadIdx.x;
  if (i >= N_NODES * C / 4) return;
  float4 v = ((float4*)out)[i];
  const int c4 = i & 31;
  const float4 sc = ((const float4*)scale)[c4];
  const float4 sh = ((const float4*)shift)[c4];
  v.x = fmaxf(0.f, fmaf(v.x, sc.x, sh.x));
  v.y = fmaxf(0.f, fmaf(v.y, sc.y, sh.y));
  v.z = fmaxf(0.f, fmaf(v.z, sc.z, sh.z));
  v.w = fmaxf(0.f, fmaf(v.w, sc.w, sh.w));
  ((float4*)out)[i] = v;
}

extern "C" void kernel_launch(void* const* d_in, const int* in_sizes, int n_in,
                              void* d_out, int out_size, void* d_ws, size_t ws_size,
                              hipStream_t stream) {
  const float* x = (const float*)d_in[0];
  const int* ei = (const int*)d_in[1];
  const float* W = (const float*)d_in[2];
  const float* att_src = (const float*)d_in[3];
  const float* att_dst = (const float*)d_in[4];
  const float* bias = (const float*)d_in[5];
  const float* gamma = (const float*)d_in[6];
  const float* beta = (const float*)d_in[7];
  float* out = (float*)d_out;

  char* base = (char*)d_ws;
  size_t off = 0;
  auto alloc = [&](size_t bytes) {
    void* p = base + off;
    off = (off + bytes + 255) & ~(size_t)255;
    return p;
  };

  float* h = (float*)alloc((size_t)N_NODES * C * 4);
  float* a_src = (float*)alloc((size_t)N_NODES * HEADS * 4);
  float* a_dst = (float*)alloc((size_t)N_NODES * HEADS * 4);
  int* srcs_s = (int*)alloc((size_t)E_TOTAL * 4);
  int* offs = (int*)alloc((size_t)N_NODES * 4);
  int* bsums = (int*)alloc(256 * 4);
  float* scale = (float*)alloc(C * 4);
  float* shift = (float*)alloc(C * 4);
  // ---- zeroed region (single memset) ----
  const size_t zoff = off;
  int* counts = (int*)alloc((size_t)N_NODES * 4);
  int* cursor = (int*)alloc((size_t)N_NODES * 4);
  float* bnsum = (float*)alloc(C * 4);
  float* bnsq = (float*)alloc(C * 4);
  const size_t zbytes = off - zoff;
  hipMemsetAsync(base + zoff, 0, zbytes, stream);

  k_gemm_att<<<N_NODES / 8, 128, 0, stream>>>(x, W, att_src, att_dst, h, a_src, a_dst);
  k_hist<<<(E_TOTAL + 255) / 256, 256, 0, stream>>>(ei, counts);
  k_scan1<<<SCAN_BLKS, 256, 0, stream>>>(counts, offs, bsums);
  k_scan2<<<1, 256, 0, stream>>>(bsums);
  k_scan3<<<SCAN_BLKS, 256, 0, stream>>>(offs, bsums);
  k_edge_fill<<<(E_TOTAL + 255) / 256, 256, 0, stream>>>(ei, offs, cursor, srcs_s);
  k_agg<<<N_NODES / 8, 128, 0, stream>>>(h, srcs_s, a_src, a_dst, offs, counts, bias, out,
                                         bnsum, bnsq);
  k_bnfin<<<1, 128, 0, stream>>>(bnsum, bnsq, gamma, beta, scale, shift);
  k_norm<<<(N_NODES * C / 4 + 255) / 256, 256, 0, stream>>>(out, scale, shift);
}

// Round 6
// 395.799 us; speedup vs baseline: 2.9149x; 1.1484x over previous
//
#include <hip/hip_runtime.h>
#include <hip/hip_bf16.h>

#define N_NODES 50000
#define N_EDGES 800000
#define E_TOTAL (N_EDGES + N_NODES)
#define HEADS 8
#define HD 16
#define C 128            // HEADS*HD == IN_CH
#define NEG_SLOPE 0.2f
#define BN_EPS 1e-5f
#define SCAN_BLKS ((N_NODES + 255) / 256)

__device__ __forceinline__ float blo(unsigned w) { return __uint_as_float(w << 16); }
__device__ __forceinline__ float bhi(unsigned w) { return __uint_as_float(w & 0xffff0000u); }

// ---- 1) h = x @ W (bf16 out) + per-head a_src/a_dst reductions ----
// block = 128 threads (thread = output channel), 8 nodes per block
__global__ __launch_bounds__(128) void k_gemm_att(
    const float* __restrict__ x, const float* __restrict__ W,
    const float* __restrict__ att_src, const float* __restrict__ att_dst,
    __hip_bfloat16* __restrict__ h, float* __restrict__ a_src, float* __restrict__ a_dst) {
  __shared__ float xs[8 * C];
  const int t = threadIdx.x;
  const int node0 = blockIdx.x * 8;
  const float* xsrc = x + (size_t)node0 * C;
#pragma unroll
  for (int i = 0; i < 8; ++i) xs[t + i * 128] = xsrc[t + i * 128];
  __syncthreads();

  float acc[8] = {0.f, 0.f, 0.f, 0.f, 0.f, 0.f, 0.f, 0.f};
  for (int k4 = 0; k4 < 32; ++k4) {
    const float w0 = W[(4 * k4 + 0) * C + t];
    const float w1 = W[(4 * k4 + 1) * C + t];
    const float w2 = W[(4 * k4 + 2) * C + t];
    const float w3 = W[(4 * k4 + 3) * C + t];
#pragma unroll
    for (int n = 0; n < 8; ++n) {
      const float4 xq = *(const float4*)&xs[n * C + 4 * k4];
      acc[n] = fmaf(xq.w, w3, fmaf(xq.z, w2, fmaf(xq.y, w1, fmaf(xq.x, w0, acc[n]))));
    }
  }

  const float asv = att_src[t];
  const float adv = att_dst[t];
#pragma unroll
  for (int n = 0; n < 8; ++n) {
    const int node = node0 + n;
    h[(size_t)node * C + t] = __float2bfloat16(acc[n]);
    float s = acc[n] * asv;
    float d = acc[n] * adv;
#pragma unroll
    for (int off = 8; off >= 1; off >>= 1) {
      s += __shfl_xor(s, off, 16);
      d += __shfl_xor(d, off, 16);
    }
    if ((t & 15) == 0) {
      a_src[node * HEADS + (t >> 4)] = s;
      a_dst[node * HEADS + (t >> 4)] = d;
    }
  }
}

// ---- 2) histogram of dst degrees (incl. self loops) ----
__global__ void k_hist(const int* __restrict__ ei, int* __restrict__ counts) {
  const int e = blockIdx.x * blockDim.x + threadIdx.x;
  if (e >= E_TOTAL) return;
  const int dst = (e < N_EDGES) ? ei[N_EDGES + e] : (e - N_EDGES);
  atomicAdd(&counts[dst], 1);
}

// ---- 3) exclusive scan of counts -> offs ----
__global__ __launch_bounds__(256) void k_scan1(const int* __restrict__ counts,
                                               int* __restrict__ offs,
                                               int* __restrict__ bsums) {
  __shared__ int s[256];
  const int t = threadIdx.x;
  const int i = blockIdx.x * 256 + t;
  const int c = (i < N_NODES) ? counts[i] : 0;
  s[t] = c;
  __syncthreads();
  for (int off = 1; off < 256; off <<= 1) {
    int v = 0;
    if (t >= off) v = s[t - off];
    __syncthreads();
    if (t >= off) s[t] += v;
    __syncthreads();
  }
  if (i < N_NODES) offs[i] = s[t] - c;
  if (t == 255) bsums[blockIdx.x] = s[255];
}

__global__ __launch_bounds__(256) void k_scan2(int* __restrict__ bsums) {
  __shared__ int s[256];
  const int t = threadIdx.x;
  const int c = (t < SCAN_BLKS) ? bsums[t] : 0;
  s[t] = c;
  __syncthreads();
  for (int off = 1; off < 256; off <<= 1) {
    int v = 0;
    if (t >= off) v = s[t - off];
    __syncthreads();
    if (t >= off) s[t] += v;
    __syncthreads();
  }
  if (t < SCAN_BLKS) bsums[t] = s[t] - c;
}

__global__ __launch_bounds__(256) void k_scan3(int* __restrict__ offs,
                                               const int* __restrict__ bsums) {
  const int i = blockIdx.x * 256 + threadIdx.x;
  if (i < N_NODES) offs[i] += bsums[blockIdx.x];
}

// ---- 4) fill CSR (sorted-by-dst source list) ----
__global__ void k_edge_fill(const int* __restrict__ ei,
                            const int* __restrict__ offs, int* __restrict__ cursor,
                            int* __restrict__ srcs_s) {
  const int e = blockIdx.x * blockDim.x + threadIdx.x;
  if (e >= E_TOTAL) return;
  int src, dst;
  if (e < N_EDGES) {
    src = ei[e];
    dst = ei[N_EDGES + e];
  } else {
    src = dst = e - N_EDGES;
  }
  const int pos = offs[dst] + atomicAdd(&cursor[dst], 1);
  srcs_s[pos] = src;
}

// ---- 5) gather aggregate, single pass (no segment max: logits bounded) ----
// 256 threads = 4 independent waves; wave = 1 node (64 lanes x 2 channels);
// each wave does 2 nodes serially -> block covers 8 nodes.
__global__ __launch_bounds__(256) void k_agg(
    const __hip_bfloat16* __restrict__ hb, const int* __restrict__ srcs_s,
    const float* __restrict__ a_src, const float* __restrict__ a_dst,
    const int* __restrict__ offs, const int* __restrict__ counts,
    const float* __restrict__ bias, float* __restrict__ out,
    float* __restrict__ bnsum, float* __restrict__ bnsq) {
  const int t = threadIdx.x;
  const int wv = t >> 6;        // wave 0..3
  const int l = t & 63;         // lane
  const int hh = l >> 3;        // head (channels 2l,2l+1 are in head l>>3)
  const int c0 = 2 * l;
  const float2 bv = ((const float2*)bias)[l];
  const unsigned* __restrict__ h2 = (const unsigned*)hb;

  float bs0 = 0.f, bs1 = 0.f, bq0 = 0.f, bq1 = 0.f;
#pragma unroll 1
  for (int n = 0; n < 2; ++n) {
    const int node = blockIdx.x * 8 + wv * 2 + n;
    const int beg = offs[node];
    const int end = beg + counts[node];
    const float adv = a_dst[node * HEADS + hh];
    float acc0 = 0.f, acc1 = 0.f, den = 0.f;
    int j = beg;
    for (; j + 1 < end; j += 2) {
      const int s0 = srcs_s[j];
      const int s1 = srcs_s[j + 1];
      float v0 = a_src[s0 * HEADS + hh] + adv;
      float v1 = a_src[s1 * HEADS + hh] + adv;
      v0 = (v0 > 0.f) ? v0 : NEG_SLOPE * v0;
      v1 = (v1 > 0.f) ? v1 : NEG_SLOPE * v1;
      const unsigned w0 = h2[(size_t)s0 * 64 + l];
      const unsigned w1 = h2[(size_t)s1 * 64 + l];
      const float e0 = __expf(v0);
      const float e1 = __expf(v1);
      den += e0 + e1;
      acc0 = fmaf(e0, blo(w0), acc0);
      acc1 = fmaf(e0, bhi(w0), acc1);
      acc0 = fmaf(e1, blo(w1), acc0);
      acc1 = fmaf(e1, bhi(w1), acc1);
    }
    if (j < end) {
      const int s0 = srcs_s[j];
      float v0 = a_src[s0 * HEADS + hh] + adv;
      v0 = (v0 > 0.f) ? v0 : NEG_SLOPE * v0;
      const unsigned w0 = h2[(size_t)s0 * 64 + l];
      const float e0 = __expf(v0);
      den += e0;
      acc0 = fmaf(e0, blo(w0), acc0);
      acc1 = fmaf(e0, bhi(w0), acc1);
    }
    const float inv = 1.f / (den + 1e-16f);
    const float val0 = fmaf(acc0, inv, bv.x);
    const float val1 = fmaf(acc1, inv, bv.y);
    float2 o;
    o.x = val0;
    o.y = val1;
    ((float2*)out)[(size_t)node * 64 + l] = o;
    bs0 += val0;
    bs1 += val1;
    bq0 += val0 * val0;
    bq1 += val1 * val1;
  }

  // per-block BN reduction (4 waves -> 1) then one atomic per channel
  __shared__ float red[4][128];
  red[wv][c0] = bs0;
  red[wv][c0 + 1] = bs1;
  __syncthreads();
  if (t < 128) atomicAdd(&bnsum[t], red[0][t] + red[1][t] + red[2][t] + red[3][t]);
  __syncthreads();
  red[wv][c0] = bq0;
  red[wv][c0 + 1] = bq1;
  __syncthreads();
  if (t < 128) atomicAdd(&bnsq[t], red[0][t] + red[1][t] + red[2][t] + red[3][t]);
}

// ---- 6) finalize BN scale/shift ----
__global__ __launch_bounds__(128) void k_bnfin(const float* __restrict__ bnsum,
                                               const float* __restrict__ bnsq,
                                               const float* __restrict__ gamma,
                                               const float* __restrict__ beta,
                                               float* __restrict__ scale,
                                               float* __restrict__ shift) {
  const int t = threadIdx.x;
  const float invN = 1.0f / (float)N_NODES;
  const float mean = bnsum[t] * invN;
  const float var = bnsq[t] * invN - mean * mean;
  const float sc = gamma[t] * rsqrtf(var + BN_EPS);
  scale[t] = sc;
  shift[t] = beta[t] - mean * sc;
}

// ---- 7) normalize + ReLU ----
__global__ __launch_bounds__(256) void k_norm(float* __restrict__ out,
                                              const float* __restrict__ scale,
                                              const float* __restrict__ shift) {
  const int i = blockIdx.x * blockDim.x + threadIdx.x;
  if (i >= N_NODES * C / 4) return;
  float4 v = ((float4*)out)[i];
  const int c4 = i & 31;
  const float4 sc = ((const float4*)scale)[c4];
  const float4 sh = ((const float4*)shift)[c4];
  v.x = fmaxf(0.f, fmaf(v.x, sc.x, sh.x));
  v.y = fmaxf(0.f, fmaf(v.y, sc.y, sh.y));
  v.z = fmaxf(0.f, fmaf(v.z, sc.z, sh.z));
  v.w = fmaxf(0.f, fmaf(v.w, sc.w, sh.w));
  ((float4*)out)[i] = v;
}

extern "C" void kernel_launch(void* const* d_in, const int* in_sizes, int n_in,
                              void* d_out, int out_size, void* d_ws, size_t ws_size,
                              hipStream_t stream) {
  const float* x = (const float*)d_in[0];
  const int* ei = (const int*)d_in[1];
  const float* W = (const float*)d_in[2];
  const float* att_src = (const float*)d_in[3];
  const float* att_dst = (const float*)d_in[4];
  const float* bias = (const float*)d_in[5];
  const float* gamma = (const float*)d_in[6];
  const float* beta = (const float*)d_in[7];
  float* out = (float*)d_out;

  char* base = (char*)d_ws;
  size_t off = 0;
  auto alloc = [&](size_t bytes) {
    void* p = base + off;
    off = (off + bytes + 255) & ~(size_t)255;
    return p;
  };

  __hip_bfloat16* hb = (__hip_bfloat16*)alloc((size_t)N_NODES * C * 2);
  float* a_src = (float*)alloc((size_t)N_NODES * HEADS * 4);
  float* a_dst = (float*)alloc((size_t)N_NODES * HEADS * 4);
  int* srcs_s = (int*)alloc((size_t)E_TOTAL * 4);
  int* offs = (int*)alloc((size_t)N_NODES * 4);
  int* bsums = (int*)alloc(256 * 4);
  float* scale = (float*)alloc(C * 4);
  float* shift = (float*)alloc(C * 4);
  // ---- zeroed region (single memset) ----
  const size_t zoff = off;
  int* counts = (int*)alloc((size_t)N_NODES * 4);
  int* cursor = (int*)alloc((size_t)N_NODES * 4);
  float* bnsum = (float*)alloc(C * 4);
  float* bnsq = (float*)alloc(C * 4);
  const size_t zbytes = off - zoff;
  hipMemsetAsync(base + zoff, 0, zbytes, stream);

  k_gemm_att<<<N_NODES / 8, 128, 0, stream>>>(x, W, att_src, att_dst, hb, a_src, a_dst);
  k_hist<<<(E_TOTAL + 255) / 256, 256, 0, stream>>>(ei, counts);
  k_scan1<<<SCAN_BLKS, 256, 0, stream>>>(counts, offs, bsums);
  k_scan2<<<1, 256, 0, stream>>>(bsums);
  k_scan3<<<SCAN_BLKS, 256, 0, stream>>>(offs, bsums);
  k_edge_fill<<<(E_TOTAL + 255) / 256, 256, 0, stream>>>(ei, offs, cursor, srcs_s);
  k_agg<<<N_NODES / 8, 256, 0, stream>>>(hb, srcs_s, a_src, a_dst, offs, counts, bias, out,
                                         bnsum, bnsq);
  k_bnfin<<<1, 128, 0, stream>>>(bnsum, bnsq, gamma, beta, scale, shift);
  k_norm<<<(N_NODES * C / 4 + 255) / 256, 256, 0, stream>>>(out, scale, shift);
}